// Round 14
// baseline (1242.724 us; speedup 1.0000x reference)
//
#include <hip/hip_runtime.h>
#include <hip/hip_cooperative_groups.h>
#include <math.h>

namespace cg = cooperative_groups;

#define NN 50000
#define NE 800000
#define HEADS 4
#define HID 64
#define HD 256          // HEADS*HID flattened feature dim
#define NEG_SLOPE 0.2f
#define CBLK 1024       // cooperative grid: 4 blocks/CU (24 VGPR, 1KB LDS -> co-resident)
#define CTHR 256

typedef __attribute__((ext_vector_type(8))) short short8;
typedef __attribute__((ext_vector_type(4))) float f32x4;

__device__ __forceinline__ unsigned short f2bf(float f) {
    unsigned u = __float_as_uint(f);
    u += 0x7fff + ((u >> 16) & 1);          // RNE
    return (unsigned short)(u >> 16);
}
__device__ __forceinline__ float bf2f(unsigned short b) {
    return __uint_as_float(((unsigned)b) << 16);
}

// ---------------- W fragment-major split (coalesced GEMM B loads) ----------------
// Wf[(((kb*16 + tile)*2 + h)*64 + lane)*8 + j]
//   = split(W[kb*32 + (lane>>4)*8 + j][tile*16 + (lane&15)]),  h=0 hi, h=1 lo.
__device__ __forceinline__ void wsplit_one(const float* W, unsigned short* Wf, int idx) {
    int lane = idx & 63;
    int tile = (idx >> 6) & 15;
    int kb   = idx >> 10;
    int col  = tile * 16 + (lane & 15);
    int krow = kb * 32 + (lane >> 4) * 8;
    unsigned short* p = Wf + ((size_t)(kb * 16 + tile) * 2 * 64 + lane) * 8;
#pragma unroll
    for (int j = 0; j < 8; j++) {
        float v = W[(size_t)(krow + j) * HD + col];
        unsigned short h = f2bf(v);
        unsigned short l = f2bf(v - bf2f(h));
        p[j] = h;
        p[512 + j] = l;            // lo region: +64*8
    }
}

#define XSPLIT4 (NN * 128 / 4)     // 1,600,000 float4s

// ---------------- cooperative build: prep (X/W splits) + full dst-CSR ----------------
// One dispatch replacing {prep, memset, count, chunk_sum, rowptr, scatter}.
// 1024 blocks (4/CU) -> 262144 threads: latency-bound atomic phases have 4x R13's TLP.
__global__ __launch_bounds__(CTHR) void build_kernel(
    const float* __restrict__ X, ushort* __restrict__ Xh, ushort* __restrict__ Xl,
    const float* __restrict__ W0, unsigned short* __restrict__ Wf0,
    const float* __restrict__ W1, unsigned short* __restrict__ Wf1,
    const float* __restrict__ W2, unsigned short* __restrict__ Wf2,
    const int* __restrict__ src, const int* __restrict__ dst,
    int* __restrict__ cnt, int* __restrict__ bsum,
    int* __restrict__ rowptr, int* __restrict__ cursor, int* __restrict__ csr_src) {
    cg::grid_group grid = cg::this_grid();
    __shared__ int sbuf[CTHR];
    int t = threadIdx.x;
    int gtid = blockIdx.x * CTHR + t;
    const int gsz = CBLK * CTHR;            // 262144

    // 0. zero counts
    for (int i = gtid; i < NN; i += gsz) cnt[i] = 0;

    // 1. prep: layer-0 X -> row-major hi/lo bf16 (coalesced)
    for (int i = gtid; i < XSPLIT4; i += gsz) {
        float4 v = ((const float4*)X)[i];
        ushort4 h, l;
        h.x = f2bf(v.x); l.x = f2bf(v.x - bf2f(h.x));
        h.y = f2bf(v.y); l.y = f2bf(v.y - bf2f(h.y));
        h.z = f2bf(v.z); l.z = f2bf(v.z - bf2f(h.z));
        h.w = f2bf(v.w); l.w = f2bf(v.w - bf2f(h.w));
        ((ushort4*)Xh)[i] = h;
        ((ushort4*)Xl)[i] = l;
    }
    // 2. prep: W fragment-major splits (3 layers)
    const int n0 = 4 * 16 * 64;             // K=128
    const int n1 = 8 * 16 * 64;             // K=256
    for (int i = gtid; i < n0 + 2 * n1; i += gsz) {
        if (i < n0) wsplit_one(W0, Wf0, i);
        else if (i < n0 + n1) wsplit_one(W1, Wf1, i - n0);
        else wsplit_one(W2, Wf2, i - n0 - n1);
    }
    grid.sync();

    // 3. count edges per dst
    for (int i = gtid; i < NE; i += gsz) atomicAdd(&cnt[dst[i]], 1);
    grid.sync();

    // 4a. block-local inclusive scan (node = gtid; <=1 node/thread since gsz > NN)
    int myCnt = (gtid < NN) ? cnt[gtid] : 0;
    sbuf[t] = myCnt; __syncthreads();
    for (int off = 1; off < CTHR; off <<= 1) {
        int tmp = (t >= off) ? sbuf[t - off] : 0;
        __syncthreads();
        sbuf[t] += tmp;
        __syncthreads();
    }
    int incl = sbuf[t];
    if (t == CTHR - 1) bsum[blockIdx.x] = incl;
    grid.sync();

    // 4b. block 0: exclusive scan of CBLK block sums (4 values/thread)
    if (blockIdx.x == 0) {
        int v0 = bsum[t * 4 + 0], v1 = bsum[t * 4 + 1];
        int v2 = bsum[t * 4 + 2], v3 = bsum[t * 4 + 3];
        int local = v0 + v1 + v2 + v3;
        __syncthreads();
        sbuf[t] = local; __syncthreads();
        for (int off = 1; off < CTHR; off <<= 1) {
            int tmp = (t >= off) ? sbuf[t - off] : 0;
            __syncthreads();
            sbuf[t] += tmp;
            __syncthreads();
        }
        int run = sbuf[t] - local;
        bsum[t * 4 + 0] = run; run += v0;
        bsum[t * 4 + 1] = run; run += v1;
        bsum[t * 4 + 2] = run; run += v2;
        bsum[t * 4 + 3] = run;
    }
    grid.sync();

    // 4c. write rowptr + cursor
    if (gtid < NN) {
        int excl = incl - myCnt + bsum[blockIdx.x];
        rowptr[gtid] = excl;
        cursor[gtid] = excl;
    }
    if (gtid == 0) rowptr[NN] = NE;
    grid.sync();

    // 5. scatter
    for (int i = gtid; i < NE; i += gsz) {
        int p = atomicAdd(&cursor[dst[i]], 1);
        csr_src[p] = src[i];
    }
}

// ---------------- MFMA GEMM + fused el/er, LDS-staged A ----------------
// H[N,256] = (Xhi+Xlo)[N,K] @ W[K,256], bf16 hi/lo (3 MFMA products, lo*lo dropped).
// Block: 64 rows x 256 cols, 4 waves; wave w owns head w's 64 cols.
// A: row-major global -> registers (coalesced 64B/row) -> fragment-major LDS
//    (b128 conflict-free) -> ds_read_b128 fragments. W: fragment-major global.
template <int K>
__global__ __launch_bounds__(256, 3) void mfma_gemm_kernel(
    const ushort* __restrict__ Xh, const ushort* __restrict__ Xl,
    const unsigned short* __restrict__ Wf,
    float* __restrict__ H,
    const float* __restrict__ al, const float* __restrict__ ar,
    float* __restrict__ el, float* __restrict__ er) {
    constexpr int KB = K / 32;     // k-blocks
    __shared__ ushort ldsA[4 * 2 * 64 * 8];   // [r][h][flane][8] = 8 KB
    int tid = threadIdx.x;
    int w = tid >> 6;              // wave index = head
    int lane = tid & 63;
    int rowBase = blockIdx.x * 64;
    int mrow = lane & 15;          // C: col within tile
    int q = lane >> 4;             // quad

    f32x4 acc[4][4];
#pragma unroll
    for (int r = 0; r < 4; r++)
#pragma unroll
        for (int c = 0; c < 4; c++) {
            f32x4 z = {0.f, 0.f, 0.f, 0.f};
            acc[r][c] = z;
        }

    // staging thread mapping: row = tid>>2 (0..63), qq = tid&3
    int srow = tid >> 2, qq = tid & 3;
    int grow = rowBase + srow;
    grow = grow < NN ? grow : NN - 1;      // clamp; OOB rows never stored
    const ushort* xhp = Xh + (size_t)grow * K + qq * 8;
    const ushort* xlp = Xl + (size_t)grow * K + qq * 8;
    int sr = srow >> 4, smrow = srow & 15;
    int flane = qq * 16 + smrow;
    ushort* ldsWhi = &ldsA[((size_t)(sr * 2 + 0) * 64 + flane) * 8];
    ushort* ldsWlo = &ldsA[((size_t)(sr * 2 + 1) * 64 + flane) * 8];

    short8 sAh = *(const short8*)xhp;
    short8 sAl = *(const short8*)xlp;

    for (int kb = 0; kb < KB; kb++) {
        __syncthreads();                   // previous iter's LDS reads done
        *(short8*)ldsWhi = sAh;
        *(short8*)ldsWlo = sAl;
        __syncthreads();
        if (kb + 1 < KB) {                 // prefetch next A tile (overlaps compute)
            sAh = *(const short8*)(xhp + (kb + 1) * 32);
            sAl = *(const short8*)(xlp + (kb + 1) * 32);
        }
        short8 Wh[4], Wl_[4];
#pragma unroll
        for (int c = 0; c < 4; c++) {
            const unsigned short* wp =
                Wf + (((size_t)(kb * 16 + w * 4 + c) * 2) * 64 + lane) * 8;
            Wh[c]  = *(const short8*)wp;
            Wl_[c] = *(const short8*)(wp + 512);
        }
        short8 Ah[4], Al_[4];
#pragma unroll
        for (int r = 0; r < 4; r++) {
            Ah[r]  = *(const short8*)&ldsA[((size_t)(r * 2 + 0) * 64 + lane) * 8];
            Al_[r] = *(const short8*)&ldsA[((size_t)(r * 2 + 1) * 64 + lane) * 8];
        }
#pragma unroll
        for (int c = 0; c < 4; c++)
#pragma unroll
            for (int r = 0; r < 4; r++) {
                acc[r][c] = __builtin_amdgcn_mfma_f32_16x16x32_bf16(Ah[r],  Wh[c],  acc[r][c], 0, 0, 0);
                acc[r][c] = __builtin_amdgcn_mfma_f32_16x16x32_bf16(Ah[r],  Wl_[c], acc[r][c], 0, 0, 0);
                acc[r][c] = __builtin_amdgcn_mfma_f32_16x16x32_bf16(Al_[r], Wh[c],  acc[r][c], 0, 0, 0);
            }
    }

    // --- epilogue: store H + fused el/er (head w) ---
    int n0 = w * 64;
    float alv[4], arv[4];
#pragma unroll
    for (int c = 0; c < 4; c++) {
        alv[c] = al[n0 + c * 16 + mrow];
        arv[c] = ar[n0 + c * 16 + mrow];
    }
#pragma unroll
    for (int r = 0; r < 4; r++) {
        float pl[4] = {0.f, 0.f, 0.f, 0.f};
        float pr[4] = {0.f, 0.f, 0.f, 0.f};
#pragma unroll
        for (int c = 0; c < 4; c++)
#pragma unroll
            for (int g = 0; g < 4; g++) {
                pl[g] += acc[r][c][g] * alv[c];
                pr[g] += acc[r][c][g] * arv[c];
            }
#pragma unroll
        for (int g = 0; g < 4; g++) {
#pragma unroll
            for (int off = 1; off < 16; off <<= 1) {
                pl[g] += __shfl_xor(pl[g], off);
                pr[g] += __shfl_xor(pr[g], off);
            }
        }
#pragma unroll
        for (int g = 0; g < 4; g++) {
            int row = rowBase + r * 16 + q * 4 + g;
            if (row < NN) {
#pragma unroll
                for (int c = 0; c < 4; c++)
                    H[(size_t)row * HD + n0 + c * 16 + mrow] = acc[r][c][g];
                if (mrow == 0) {
                    el[row * 4 + w] = pl[g];
                    er[row * 4 + w] = pr[g];
                }
            }
        }
    }
}

// ---------------- GAT per-node: single-pass flash softmax, unroll-2 ----------------
__device__ __forceinline__ float lrelu(float x) { return x > 0.f ? x : NEG_SLOPE * x; }

template <int FINAL>
__global__ __launch_bounds__(256) void gat_node_kernel(
    const float* __restrict__ H, const float* __restrict__ el, const float* __restrict__ er,
    const int* __restrict__ rowptr, const int* __restrict__ csr_src,
    ushort* __restrict__ out_hi, ushort* __restrict__ out_lo,
    const float* __restrict__ Wout, const float* __restrict__ bout,
    float* __restrict__ final_out) {
    int wave = threadIdx.x >> 6, lane = threadIdx.x & 63;
    int v = blockIdx.x * 4 + wave;
    if (v >= NN) return;
    int beg = rowptr[v], end = rowptr[v + 1];

    int hh = lane >> 4;                    // head for this lane's feature slice
    float er_h = er[v * 4 + hh];

    float m = -INFINITY;
    float ssum = 0.f;
    float4 acc = make_float4(0.f, 0.f, 0.f, 0.f);

    int idx = beg;
    for (; idx + 2 <= end; idx += 2) {
        int s0 = csr_src[idx];
        int s1 = csr_src[idx + 1];
        float el0 = el[s0 * 4 + hh];
        float el1 = el[s1 * 4 + hh];
        float4 h0 = *(const float4*)&H[(long)s0 * HD + lane * 4];
        float4 h1 = *(const float4*)&H[(long)s1 * HD + lane * 4];
        float e0 = lrelu(el0 + er_h);
        float e1 = lrelu(el1 + er_h);
        float mn = fmaxf(m, fmaxf(e0, e1));
        float sc = __expf(m - mn);
        float w0 = __expf(e0 - mn);
        float w1 = __expf(e1 - mn);
        ssum = ssum * sc + w0 + w1;
        acc.x = acc.x * sc + w0 * h0.x + w1 * h1.x;
        acc.y = acc.y * sc + w0 * h0.y + w1 * h1.y;
        acc.z = acc.z * sc + w0 * h0.z + w1 * h1.z;
        acc.w = acc.w * sc + w0 * h0.w + w1 * h1.w;
        m = mn;
    }
    if (idx < end) {
        int s0 = csr_src[idx];
        float el0 = el[s0 * 4 + hh];
        float4 h0 = *(const float4*)&H[(long)s0 * HD + lane * 4];
        float e0 = lrelu(el0 + er_h);
        float mn = fmaxf(m, e0);
        float sc = __expf(m - mn);
        float w0 = __expf(e0 - mn);
        ssum = ssum * sc + w0;
        acc.x = acc.x * sc + w0 * h0.x;
        acc.y = acc.y * sc + w0 * h0.y;
        acc.z = acc.z * sc + w0 * h0.z;
        acc.w = acc.w * sc + w0 * h0.w;
    }

    float inv = 1.0f / (ssum + 1e-9f);
    acc.x *= inv; acc.y *= inv; acc.z *= inv; acc.w *= inv;

    // elu
    acc.x = acc.x > 0.f ? acc.x : expm1f(acc.x);
    acc.y = acc.y > 0.f ? acc.y : expm1f(acc.y);
    acc.z = acc.z > 0.f ? acc.z : expm1f(acc.z);
    acc.w = acc.w > 0.f ? acc.w : expm1f(acc.w);

    if (!FINAL) {
        // row-major hi/lo bf16 (contiguous 512B/row/buffer writes) — next GEMM's A
        ushort4 hv, lv;
        hv.x = f2bf(acc.x); lv.x = f2bf(acc.x - bf2f(hv.x));
        hv.y = f2bf(acc.y); lv.y = f2bf(acc.y - bf2f(hv.y));
        hv.z = f2bf(acc.z); lv.z = f2bf(acc.z - bf2f(hv.z));
        hv.w = f2bf(acc.w); lv.w = f2bf(acc.w - bf2f(hv.w));
        *(ushort4*)&out_hi[(size_t)v * HD + lane * 4] = hv;
        *(ushort4*)&out_lo[(size_t)v * HD + lane * 4] = lv;
    } else {
        // mean over heads (lanes l, l^16, l^32 hold same d-range, different head)
        acc.x += __shfl_xor(acc.x, 16); acc.x += __shfl_xor(acc.x, 32);
        acc.y += __shfl_xor(acc.y, 16); acc.y += __shfl_xor(acc.y, 32);
        acc.z += __shfl_xor(acc.z, 16); acc.z += __shfl_xor(acc.z, 32);
        acc.w += __shfl_xor(acc.w, 16); acc.w += __shfl_xor(acc.w, 32);
        float4 w4 = *(const float4*)&Wout[(lane & 15) * 4];
        float p = 0.25f * (acc.x * w4.x + acc.y * w4.y + acc.z * w4.z + acc.w * w4.w);
        p += __shfl_xor(p, 1);
        p += __shfl_xor(p, 2);
        p += __shfl_xor(p, 4);
        p += __shfl_xor(p, 8);
        if (lane == 0) final_out[v] = fmaxf(p + bout[0], 0.f);
    }
}

extern "C" void kernel_launch(void* const* d_in, const int* in_sizes, int n_in,
                              void* d_out, int out_size, void* d_ws, size_t ws_size,
                              hipStream_t stream) {
    const float* x    = (const float*)d_in[0];
    const int*   src  = (const int*)d_in[1];
    const int*   dst  = (const int*)d_in[2];
    const float* W0   = (const float*)d_in[3];
    const float* al0  = (const float*)d_in[4];
    const float* ar0  = (const float*)d_in[5];
    const float* W1   = (const float*)d_in[6];
    const float* al1  = (const float*)d_in[7];
    const float* ar1  = (const float*)d_in[8];
    const float* W2   = (const float*)d_in[9];
    const float* al2  = (const float*)d_in[10];
    const float* ar2  = (const float*)d_in[11];
    const float* Wout = (const float*)d_in[12];
    const float* bout = (const float*)d_in[13];
    float* outp = (float*)d_out;

    char* ws = (char*)d_ws;
    size_t off = 0;
    auto carve = [&](size_t n) -> char* {
        char* p = ws + off;
        off += (n + 255) & ~(size_t)255;
        return p;
    };
    float*  h_buf  = (float*)carve((size_t)NN * HD * 4);
    ushort* xh     = (ushort*)carve((size_t)NN * HD * 2);   // A hi, row-major
    ushort* xl     = (ushort*)carve((size_t)NN * HD * 2);   // A lo, row-major
    float*  el     = (float*)carve((size_t)NN * HEADS * 4);
    float*  er     = (float*)carve((size_t)NN * HEADS * 4);
    int*    cnt    = (int*)carve((size_t)NN * 4);
    int*    cursor = (int*)carve((size_t)NN * 4);
    int*    rowptr = (int*)carve((size_t)(NN + 1) * 4);
    int*    csr_src= (int*)carve((size_t)NE * 4);
    int*    bsum   = (int*)carve(CBLK * 4);
    unsigned short* Wf0 = (unsigned short*)carve((size_t)4 * 16 * 64 * 16 * 2);   // K=128
    unsigned short* Wf1 = (unsigned short*)carve((size_t)8 * 16 * 64 * 16 * 2);   // K=256
    unsigned short* Wf2 = (unsigned short*)carve((size_t)8 * 16 * 64 * 16 * 2);   // K=256

    // ---- cooperative build: prep + full CSR in ONE dispatch (4 blocks/CU) ----
    void* args[] = {
        (void*)&x, (void*)&xh, (void*)&xl,
        (void*)&W0, (void*)&Wf0, (void*)&W1, (void*)&Wf1, (void*)&W2, (void*)&Wf2,
        (void*)&src, (void*)&dst,
        (void*)&cnt, (void*)&bsum, (void*)&rowptr, (void*)&cursor, (void*)&csr_src
    };
    hipLaunchCooperativeKernel((void*)build_kernel, dim3(CBLK), dim3(CTHR),
                               args, 0, stream);

    int gGemm = (NN + 63) / 64;            // 782
    int gNode = (NN + 3) / 4;

    // ---- layer 0 ----
    mfma_gemm_kernel<128><<<gGemm, 256, 0, stream>>>(xh, xl, Wf0, h_buf, al0, ar0, el, er);
    gat_node_kernel<0><<<gNode, 256, 0, stream>>>(h_buf, el, er, rowptr, csr_src,
                                                  xh, xl, nullptr, nullptr, nullptr);
    // ---- layer 1 ----
    mfma_gemm_kernel<256><<<gGemm, 256, 0, stream>>>(xh, xl, Wf1, h_buf, al1, ar1, el, er);
    gat_node_kernel<0><<<gNode, 256, 0, stream>>>(h_buf, el, er, rowptr, csr_src,
                                                  xh, xl, nullptr, nullptr, nullptr);
    // ---- layer 2 (final: fused elu + head-mean + Wout + relu) ----
    mfma_gemm_kernel<256><<<gGemm, 256, 0, stream>>>(xh, xl, Wf2, h_buf, al2, ar2, el, er);
    gat_node_kernel<1><<<gNode, 256, 0, stream>>>(h_buf, el, er, rowptr, csr_src,
                                                  nullptr, nullptr, Wout, bout, outp);
}

// Round 15
// 884.164 us; speedup vs baseline: 1.4055x; 1.4055x over previous
//
#include <hip/hip_runtime.h>
#include <math.h>

#define NN 50000
#define NE 800000
#define HEADS 4
#define HID 64
#define HD 256          // HEADS*HID flattened feature dim
#define NEG_SLOPE 0.2f
#define NCHUNK 49       // ceil(50000/1024)

typedef __attribute__((ext_vector_type(8))) short short8;
typedef __attribute__((ext_vector_type(4))) float f32x4;

__device__ __forceinline__ unsigned short f2bf(float f) {
    unsigned u = __float_as_uint(f);
    u += 0x7fff + ((u >> 16) & 1);          // RNE
    return (unsigned short)(u >> 16);
}
__device__ __forceinline__ float bf2f(unsigned short b) {
    return __uint_as_float(((unsigned)b) << 16);
}

// ---------------- CSR build (R12-proven) ----------------
__global__ void count_kernel(const int* __restrict__ dst, int* __restrict__ cnt) {
    int e = (blockIdx.x * 256 + threadIdx.x) * 2;
    if (e + 1 < NE) {
        int2 d = *(const int2*)&dst[e];
        atomicAdd(&cnt[d.x], 1);
        atomicAdd(&cnt[d.y], 1);
    } else if (e < NE) {
        atomicAdd(&cnt[dst[e]], 1);
    }
}

__global__ void chunk_sum_kernel(const int* __restrict__ cnt, int* __restrict__ csum, int n) {
    __shared__ int sdata[256];
    int base = blockIdx.x * 1024;
    int t = threadIdx.x;
    int s = 0;
    for (int i = t; i < 1024; i += 256) {
        int idx = base + i;
        if (idx < n) s += cnt[idx];
    }
    sdata[t] = s; __syncthreads();
    for (int off = 128; off > 0; off >>= 1) {
        if (t < off) sdata[t] += sdata[t + off];
        __syncthreads();
    }
    if (t == 0) csum[blockIdx.x] = sdata[0];
}

__global__ void rowptr_kernel(const int* __restrict__ cnt, const int* __restrict__ csum,
                              int* __restrict__ rowptr, int* __restrict__ cursor, int n) {
    __shared__ int buf[1024];
    __shared__ int chunkOff;
    int t = threadIdx.x;
    int idx = blockIdx.x * 1024 + t;
    if (t < 64) {
        int partial = 0;
        for (int i = t; i < blockIdx.x; i += 64) partial += csum[i];
#pragma unroll
        for (int off = 32; off > 0; off >>= 1) partial += __shfl_down(partial, off);
        if (t == 0) chunkOff = partial;
    }
    int v = (idx < n) ? cnt[idx] : 0;
    buf[t] = v; __syncthreads();
    for (int off = 1; off < 1024; off <<= 1) {
        int tmp = (t >= off) ? buf[t - off] : 0;
        __syncthreads();
        buf[t] += tmp;
        __syncthreads();
    }
    int excl = buf[t] - v + chunkOff;
    if (idx < n) { rowptr[idx] = excl; cursor[idx] = excl; }
    if (idx == n - 1) rowptr[n] = excl + v;
}

__global__ void scatter_kernel(const int* __restrict__ src, const int* __restrict__ dst,
                               int* __restrict__ cursor, int* __restrict__ csr_src) {
    int e = (blockIdx.x * 256 + threadIdx.x) * 2;
    if (e + 1 < NE) {
        int2 d = *(const int2*)&dst[e];
        int2 s = *(const int2*)&src[e];
        int p0 = atomicAdd(&cursor[d.x], 1);
        csr_src[p0] = s.x;
        int p1 = atomicAdd(&cursor[d.y], 1);
        csr_src[p1] = s.y;
    } else if (e < NE) {
        int p = atomicAdd(&cursor[dst[e]], 1);
        csr_src[p] = src[e];
    }
}

// ---------------- W fragment-major split (coalesced GEMM B loads) ----------------
__device__ __forceinline__ void wsplit_one(const float* W, unsigned short* Wf, int idx) {
    int lane = idx & 63;
    int tile = (idx >> 6) & 15;
    int kb   = idx >> 10;
    int col  = tile * 16 + (lane & 15);
    int krow = kb * 32 + (lane >> 4) * 8;
    unsigned short* p = Wf + ((size_t)(kb * 16 + tile) * 2 * 64 + lane) * 8;
#pragma unroll
    for (int j = 0; j < 8; j++) {
        float v = W[(size_t)(krow + j) * HD + col];
        unsigned short h = f2bf(v);
        unsigned short l = f2bf(v - bf2f(h));
        p[j] = h;
        p[512 + j] = l;            // lo region: +64*8
    }
}

#define XSPLIT4 (NN * 128 / 4)     // 1,600,000 float4s

__global__ void prep_kernel(const float* __restrict__ X, ushort* __restrict__ Xh,
                            ushort* __restrict__ Xl,
                            const float* __restrict__ W0, unsigned short* __restrict__ Wf0,
                            const float* __restrict__ W1, unsigned short* __restrict__ Wf1,
                            const float* __restrict__ W2, unsigned short* __restrict__ Wf2) {
    int idx = blockIdx.x * 256 + threadIdx.x;
    if (idx < XSPLIT4) {
        float4 v = ((const float4*)X)[idx];
        ushort4 h, l;
        h.x = f2bf(v.x); l.x = f2bf(v.x - bf2f(h.x));
        h.y = f2bf(v.y); l.y = f2bf(v.y - bf2f(h.y));
        h.z = f2bf(v.z); l.z = f2bf(v.z - bf2f(h.z));
        h.w = f2bf(v.w); l.w = f2bf(v.w - bf2f(h.w));
        ((ushort4*)Xh)[idx] = h;
        ((ushort4*)Xl)[idx] = l;
    }
    const int n0 = 4 * 16 * 64;            // K=128
    const int n1 = 8 * 16 * 64;            // K=256
    if (idx < n0) wsplit_one(W0, Wf0, idx);
    else if (idx < n0 + n1) wsplit_one(W1, Wf1, idx - n0);
    else if (idx < n0 + 2 * n1) wsplit_one(W2, Wf2, idx - n0 - n1);
}

// ---------------- MFMA GEMM + fused el/er, LDS-staged A (R12-proven) ----------------
template <int K>
__global__ __launch_bounds__(256, 3) void mfma_gemm_kernel(
    const ushort* __restrict__ Xh, const ushort* __restrict__ Xl,
    const unsigned short* __restrict__ Wf,
    float* __restrict__ H,
    const float* __restrict__ al, const float* __restrict__ ar,
    float* __restrict__ el, float* __restrict__ er) {
    constexpr int KB = K / 32;     // k-blocks
    __shared__ ushort ldsA[4 * 2 * 64 * 8];   // [r][h][flane][8] = 8 KB
    int tid = threadIdx.x;
    int w = tid >> 6;              // wave index = head
    int lane = tid & 63;
    int rowBase = blockIdx.x * 64;
    int mrow = lane & 15;          // C: col within tile
    int q = lane >> 4;             // quad

    f32x4 acc[4][4];
#pragma unroll
    for (int r = 0; r < 4; r++)
#pragma unroll
        for (int c = 0; c < 4; c++) {
            f32x4 z = {0.f, 0.f, 0.f, 0.f};
            acc[r][c] = z;
        }

    int srow = tid >> 2, qq = tid & 3;
    int grow = rowBase + srow;
    grow = grow < NN ? grow : NN - 1;      // clamp; OOB rows never stored
    const ushort* xhp = Xh + (size_t)grow * K + qq * 8;
    const ushort* xlp = Xl + (size_t)grow * K + qq * 8;
    int sr = srow >> 4, smrow = srow & 15;
    int flane = qq * 16 + smrow;
    ushort* ldsWhi = &ldsA[((size_t)(sr * 2 + 0) * 64 + flane) * 8];
    ushort* ldsWlo = &ldsA[((size_t)(sr * 2 + 1) * 64 + flane) * 8];

    short8 sAh = *(const short8*)xhp;
    short8 sAl = *(const short8*)xlp;

    for (int kb = 0; kb < KB; kb++) {
        __syncthreads();                   // previous iter's LDS reads done
        *(short8*)ldsWhi = sAh;
        *(short8*)ldsWlo = sAl;
        __syncthreads();
        if (kb + 1 < KB) {                 // prefetch next A tile (overlaps compute)
            sAh = *(const short8*)(xhp + (kb + 1) * 32);
            sAl = *(const short8*)(xlp + (kb + 1) * 32);
        }
        short8 Wh[4], Wl_[4];
#pragma unroll
        for (int c = 0; c < 4; c++) {
            const unsigned short* wp =
                Wf + (((size_t)(kb * 16 + w * 4 + c) * 2) * 64 + lane) * 8;
            Wh[c]  = *(const short8*)wp;
            Wl_[c] = *(const short8*)(wp + 512);
        }
        short8 Ah[4], Al_[4];
#pragma unroll
        for (int r = 0; r < 4; r++) {
            Ah[r]  = *(const short8*)&ldsA[((size_t)(r * 2 + 0) * 64 + lane) * 8];
            Al_[r] = *(const short8*)&ldsA[((size_t)(r * 2 + 1) * 64 + lane) * 8];
        }
#pragma unroll
        for (int c = 0; c < 4; c++)
#pragma unroll
            for (int r = 0; r < 4; r++) {
                acc[r][c] = __builtin_amdgcn_mfma_f32_16x16x32_bf16(Ah[r],  Wh[c],  acc[r][c], 0, 0, 0);
                acc[r][c] = __builtin_amdgcn_mfma_f32_16x16x32_bf16(Ah[r],  Wl_[c], acc[r][c], 0, 0, 0);
                acc[r][c] = __builtin_amdgcn_mfma_f32_16x16x32_bf16(Al_[r], Wh[c],  acc[r][c], 0, 0, 0);
            }
    }

    int n0 = w * 64;
    float alv[4], arv[4];
#pragma unroll
    for (int c = 0; c < 4; c++) {
        alv[c] = al[n0 + c * 16 + mrow];
        arv[c] = ar[n0 + c * 16 + mrow];
    }
#pragma unroll
    for (int r = 0; r < 4; r++) {
        float pl[4] = {0.f, 0.f, 0.f, 0.f};
        float pr[4] = {0.f, 0.f, 0.f, 0.f};
#pragma unroll
        for (int c = 0; c < 4; c++)
#pragma unroll
            for (int g = 0; g < 4; g++) {
                pl[g] += acc[r][c][g] * alv[c];
                pr[g] += acc[r][c][g] * arv[c];
            }
#pragma unroll
        for (int g = 0; g < 4; g++) {
#pragma unroll
            for (int off = 1; off < 16; off <<= 1) {
                pl[g] += __shfl_xor(pl[g], off);
                pr[g] += __shfl_xor(pr[g], off);
            }
        }
#pragma unroll
        for (int g = 0; g < 4; g++) {
            int row = rowBase + r * 16 + q * 4 + g;
            if (row < NN) {
#pragma unroll
                for (int c = 0; c < 4; c++)
                    H[(size_t)row * HD + n0 + c * 16 + mrow] = acc[r][c][g];
                if (mrow == 0) {
                    el[row * 4 + w] = pl[g];
                    er[row * 4 + w] = pr[g];
                }
            }
        }
    }
}

// ---------------- GAT per-node, XCD-sliced dims ----------------
// Block b: dim-slice (b & 7) [32 dims], node group (b >> 3). blockIdx%8 -> XCD
// round-robin pins each slice to one XCD: per-XCD H working set = 51/8 = 6.4 MB
// (~L2-resident) instead of 51 MB streamed by every XCD.
// Wave = 1 node: 8 edge-slots x 8 lanes (float4 = 32 dims). Per-slot online
// softmax, then shfl_xor(8,16,32) merge across slots.
__device__ __forceinline__ float lrelu(float x) { return x > 0.f ? x : NEG_SLOPE * x; }

template <int FINAL>
__global__ __launch_bounds__(256) void gat_slice_kernel(
    const float* __restrict__ H, const float* __restrict__ el, const float* __restrict__ er,
    const int* __restrict__ rowptr, const int* __restrict__ csr_src,
    ushort* __restrict__ out_hi, ushort* __restrict__ out_lo,
    const float* __restrict__ Wout, float* __restrict__ tmp_out) {
    int wave = threadIdx.x >> 6, lane = threadIdx.x & 63;
    int slice = blockIdx.x & 7;
    int v = (blockIdx.x >> 3) * 4 + wave;
    if (v >= NN) return;
    int hh = slice >> 1;               // head owning this slice
    int dbase = slice * 32;
    int slot = lane >> 3, dq = lane & 7;

    int beg = rowptr[v], end = rowptr[v + 1];
    float er_h = er[v * 4 + hh];

    float m = -INFINITY, ssum = 0.f;
    float4 acc = make_float4(0.f, 0.f, 0.f, 0.f);

    for (int idx = beg + slot; idx < end; idx += 8) {
        int s0 = csr_src[idx];
        float el0 = el[s0 * 4 + hh];
        float4 h0 = *(const float4*)&H[(size_t)s0 * HD + dbase + dq * 4];
        float e0 = lrelu(el0 + er_h);
        float mn = fmaxf(m, e0);
        float sc = __expf(m - mn);
        float w0 = __expf(e0 - mn);
        ssum = ssum * sc + w0;
        acc.x = acc.x * sc + w0 * h0.x;
        acc.y = acc.y * sc + w0 * h0.y;
        acc.z = acc.z * sc + w0 * h0.z;
        acc.w = acc.w * sc + w0 * h0.w;
        m = mn;
    }

    // merge across the 8 slots (lane bits 3..5)
    float M = m;
    M = fmaxf(M, __shfl_xor(M, 8));
    M = fmaxf(M, __shfl_xor(M, 16));
    M = fmaxf(M, __shfl_xor(M, 32));
    float Mc = (M == -INFINITY) ? 0.f : M;   // zero-degree guard
    float sc = __expf(m - Mc);               // m=-inf -> 0
    ssum *= sc;
    acc.x *= sc; acc.y *= sc; acc.z *= sc; acc.w *= sc;
    ssum += __shfl_xor(ssum, 8); ssum += __shfl_xor(ssum, 16); ssum += __shfl_xor(ssum, 32);
    acc.x += __shfl_xor(acc.x, 8); acc.x += __shfl_xor(acc.x, 16); acc.x += __shfl_xor(acc.x, 32);
    acc.y += __shfl_xor(acc.y, 8); acc.y += __shfl_xor(acc.y, 16); acc.y += __shfl_xor(acc.y, 32);
    acc.z += __shfl_xor(acc.z, 8); acc.z += __shfl_xor(acc.z, 16); acc.z += __shfl_xor(acc.z, 32);
    acc.w += __shfl_xor(acc.w, 8); acc.w += __shfl_xor(acc.w, 16); acc.w += __shfl_xor(acc.w, 32);

    float inv = 1.0f / (ssum + 1e-9f);
    acc.x *= inv; acc.y *= inv; acc.z *= inv; acc.w *= inv;
    // elu
    acc.x = acc.x > 0.f ? acc.x : expm1f(acc.x);
    acc.y = acc.y > 0.f ? acc.y : expm1f(acc.y);
    acc.z = acc.z > 0.f ? acc.z : expm1f(acc.z);
    acc.w = acc.w > 0.f ? acc.w : expm1f(acc.w);

    if (!FINAL) {
        if (slot == 0) {       // lanes 0..7 write the 32-dim slice (64 B/buffer)
            ushort4 hv, lv;
            hv.x = f2bf(acc.x); lv.x = f2bf(acc.x - bf2f(hv.x));
            hv.y = f2bf(acc.y); lv.y = f2bf(acc.y - bf2f(hv.y));
            hv.z = f2bf(acc.z); lv.z = f2bf(acc.z - bf2f(hv.z));
            hv.w = f2bf(acc.w); lv.w = f2bf(acc.w - bf2f(hv.w));
            size_t o = (size_t)v * HD + dbase + dq * 4;
            *(ushort4*)&out_hi[o] = hv;
            *(ushort4*)&out_lo[o] = lv;
        }
    } else {
        // partial head-mean dot: dims dbase..dbase+31 map to Wout[(slice&1)*32 ..]
        float4 w4 = *(const float4*)&Wout[(slice & 1) * 32 + dq * 4];
        float p = acc.x * w4.x + acc.y * w4.y + acc.z * w4.z + acc.w * w4.w;
        p += __shfl_xor(p, 1);
        p += __shfl_xor(p, 2);
        p += __shfl_xor(p, 4);
        if (lane == 0) atomicAdd(&tmp_out[v], 0.25f * p);
    }
}

__global__ void final_relu_kernel(float* __restrict__ out, const float* __restrict__ bout) {
    int v = blockIdx.x * 256 + threadIdx.x;
    if (v < NN) out[v] = fmaxf(out[v] + bout[0], 0.f);
}

extern "C" void kernel_launch(void* const* d_in, const int* in_sizes, int n_in,
                              void* d_out, int out_size, void* d_ws, size_t ws_size,
                              hipStream_t stream) {
    const float* x    = (const float*)d_in[0];
    const int*   src  = (const int*)d_in[1];
    const int*   dst  = (const int*)d_in[2];
    const float* W0   = (const float*)d_in[3];
    const float* al0  = (const float*)d_in[4];
    const float* ar0  = (const float*)d_in[5];
    const float* W1   = (const float*)d_in[6];
    const float* al1  = (const float*)d_in[7];
    const float* ar1  = (const float*)d_in[8];
    const float* W2   = (const float*)d_in[9];
    const float* al2  = (const float*)d_in[10];
    const float* ar2  = (const float*)d_in[11];
    const float* Wout = (const float*)d_in[12];
    const float* bout = (const float*)d_in[13];
    float* outp = (float*)d_out;

    char* ws = (char*)d_ws;
    size_t off = 0;
    auto carve = [&](size_t n) -> char* {
        char* p = ws + off;
        off += (n + 255) & ~(size_t)255;
        return p;
    };
    float*  h_buf  = (float*)carve((size_t)NN * HD * 4);
    ushort* xh     = (ushort*)carve((size_t)NN * HD * 2);   // A hi, row-major
    ushort* xl     = (ushort*)carve((size_t)NN * HD * 2);   // A lo, row-major
    float*  el     = (float*)carve((size_t)NN * HEADS * 4);
    float*  er     = (float*)carve((size_t)NN * HEADS * 4);
    int*    cnt    = (int*)carve((size_t)NN * 4);
    int*    cursor = (int*)carve((size_t)NN * 4);
    int*    rowptr = (int*)carve((size_t)(NN + 1) * 4);
    int*    csr_src= (int*)carve((size_t)NE * 4);
    int*    csum   = (int*)carve(64 * 4);
    unsigned short* Wf0 = (unsigned short*)carve((size_t)4 * 16 * 64 * 16 * 2);   // K=128
    unsigned short* Wf1 = (unsigned short*)carve((size_t)8 * 16 * 64 * 16 * 2);   // K=256
    unsigned short* Wf2 = (unsigned short*)carve((size_t)8 * 16 * 64 * 16 * 2);   // K=256

    // ---- prep: all W splits + layer-0 X split in one dispatch ----
    prep_kernel<<<(XSPLIT4 + 255) / 256, 256, 0, stream>>>(x, xh, xl, W0, Wf0, W1, Wf1, W2, Wf2);

    // ---- build dst-CSR: memset, count, chunk_sum, rowptr(+cursor), scatter ----
    hipMemsetAsync(cnt, 0, (size_t)NN * 4, stream);
    count_kernel<<<(NE / 2 + 255) / 256, 256, 0, stream>>>(dst, cnt);
    chunk_sum_kernel<<<NCHUNK, 256, 0, stream>>>(cnt, csum, NN);
    rowptr_kernel<<<NCHUNK, 1024, 0, stream>>>(cnt, csum, rowptr, cursor, NN);
    scatter_kernel<<<(NE / 2 + 255) / 256, 256, 0, stream>>>(src, dst, cursor, csr_src);
    hipMemsetAsync(outp, 0, (size_t)NN * 4, stream);   // FINAL-layer atomic accumulator

    int gGemm = (NN + 63) / 64;            // 782
    int gSlice = ((NN + 3) / 4) * 8;       // 100,000: slice = b&7, group = b>>3

    // ---- layer 0 ----
    mfma_gemm_kernel<128><<<gGemm, 256, 0, stream>>>(xh, xl, Wf0, h_buf, al0, ar0, el, er);
    gat_slice_kernel<0><<<gSlice, 256, 0, stream>>>(h_buf, el, er, rowptr, csr_src,
                                                    xh, xl, nullptr, nullptr);
    // ---- layer 1 ----
    mfma_gemm_kernel<256><<<gGemm, 256, 0, stream>>>(xh, xl, Wf1, h_buf, al1, ar1, el, er);
    gat_slice_kernel<0><<<gSlice, 256, 0, stream>>>(h_buf, el, er, rowptr, csr_src,
                                                    xh, xl, nullptr, nullptr);
    // ---- layer 2 (final: sliced partial dots -> atomic accumulate -> relu) ----
    mfma_gemm_kernel<256><<<gGemm, 256, 0, stream>>>(xh, xl, Wf2, h_buf, al2, ar2, el, er);
    gat_slice_kernel<1><<<gSlice, 256, 0, stream>>>(h_buf, el, er, rowptr, csr_src,
                                                    nullptr, nullptr, Wout, outp);
    final_relu_kernel<<<(NN + 255) / 256, 256, 0, stream>>>(outp, bout);
}

// Round 16
// 667.216 us; speedup vs baseline: 1.8626x; 1.3252x over previous
//
#include <hip/hip_runtime.h>
#include <math.h>

#define NN 50000
#define NE 800000
#define HEADS 4
#define HID 64
#define HD 256          // HEADS*HID flattened feature dim
#define NEG_SLOPE 0.2f
#define NCHUNK 49       // ceil(50000/1024)

typedef __attribute__((ext_vector_type(8))) short short8;
typedef __attribute__((ext_vector_type(4))) float f32x4;

__device__ __forceinline__ unsigned short f2bf(float f) {
    unsigned u = __float_as_uint(f);
    u += 0x7fff + ((u >> 16) & 1);          // RNE
    return (unsigned short)(u >> 16);
}
__device__ __forceinline__ float bf2f(unsigned short b) {
    return __uint_as_float(((unsigned)b) << 16);
}

// ---------------- CSR build (R12-proven; 4 edges/thread) ----------------
__global__ void count_kernel(const int* __restrict__ dst, int* __restrict__ cnt) {
    int e = (blockIdx.x * 256 + threadIdx.x) * 4;
    if (e + 3 < NE) {
        int4 d = *(const int4*)&dst[e];
        atomicAdd(&cnt[d.x], 1);
        atomicAdd(&cnt[d.y], 1);
        atomicAdd(&cnt[d.z], 1);
        atomicAdd(&cnt[d.w], 1);
    } else {
        for (int i = e; i < NE; ++i) atomicAdd(&cnt[dst[i]], 1);
    }
}

__global__ void chunk_sum_kernel(const int* __restrict__ cnt, int* __restrict__ csum, int n) {
    __shared__ int sdata[256];
    int base = blockIdx.x * 1024;
    int t = threadIdx.x;
    int s = 0;
    for (int i = t; i < 1024; i += 256) {
        int idx = base + i;
        if (idx < n) s += cnt[idx];
    }
    sdata[t] = s; __syncthreads();
    for (int off = 128; off > 0; off >>= 1) {
        if (t < off) sdata[t] += sdata[t + off];
        __syncthreads();
    }
    if (t == 0) csum[blockIdx.x] = sdata[0];
}

__global__ void rowptr_kernel(const int* __restrict__ cnt, const int* __restrict__ csum,
                              int* __restrict__ rowptr, int* __restrict__ cursor, int n) {
    __shared__ int buf[1024];
    __shared__ int chunkOff;
    int t = threadIdx.x;
    int idx = blockIdx.x * 1024 + t;
    if (t < 64) {
        int partial = 0;
        for (int i = t; i < blockIdx.x; i += 64) partial += csum[i];
#pragma unroll
        for (int off = 32; off > 0; off >>= 1) partial += __shfl_down(partial, off);
        if (t == 0) chunkOff = partial;
    }
    int v = (idx < n) ? cnt[idx] : 0;
    buf[t] = v; __syncthreads();
    for (int off = 1; off < 1024; off <<= 1) {
        int tmp = (t >= off) ? buf[t - off] : 0;
        __syncthreads();
        buf[t] += tmp;
        __syncthreads();
    }
    int excl = buf[t] - v + chunkOff;
    if (idx < n) { rowptr[idx] = excl; cursor[idx] = excl; }
    if (idx == n - 1) rowptr[n] = excl + v;
}

__global__ void scatter_kernel(const int* __restrict__ src, const int* __restrict__ dst,
                               int* __restrict__ cursor, int* __restrict__ csr_src) {
    int e = (blockIdx.x * 256 + threadIdx.x) * 4;
    if (e + 3 < NE) {
        int4 d = *(const int4*)&dst[e];
        int4 s = *(const int4*)&src[e];
        int p0 = atomicAdd(&cursor[d.x], 1); csr_src[p0] = s.x;
        int p1 = atomicAdd(&cursor[d.y], 1); csr_src[p1] = s.y;
        int p2 = atomicAdd(&cursor[d.z], 1); csr_src[p2] = s.z;
        int p3 = atomicAdd(&cursor[d.w], 1); csr_src[p3] = s.w;
    } else {
        for (int i = e; i < NE; ++i) {
            int p = atomicAdd(&cursor[dst[i]], 1);
            csr_src[p] = src[i];
        }
    }
}

// ---------------- W fragment-major split (coalesced GEMM B loads) ----------------
// Wf[(((kb*16 + tile)*2 + h)*64 + lane)*8 + j]
//   = split(W[kb*32 + (lane>>4)*8 + j][tile*16 + (lane&15)]),  h=0 hi, h=1 lo.
__device__ __forceinline__ void wsplit_one(const float* W, unsigned short* Wf, int idx) {
    int lane = idx & 63;
    int tile = (idx >> 6) & 15;
    int kb   = idx >> 10;
    int col  = tile * 16 + (lane & 15);
    int krow = kb * 32 + (lane >> 4) * 8;
    unsigned short* p = Wf + ((size_t)(kb * 16 + tile) * 2 * 64 + lane) * 8;
#pragma unroll
    for (int j = 0; j < 8; j++) {
        float v = W[(size_t)(krow + j) * HD + col];
        unsigned short h = f2bf(v);
        unsigned short l = f2bf(v - bf2f(h));
        p[j] = h;
        p[512 + j] = l;            // lo region: +64*8
    }
}

#define XSPLIT4 (NN * 128 / 4)     // 1,600,000 float4s

// prep: layer-0 X -> row-major xh/xl bf16, W splits, and cnt zeroing (drops memset dispatch)
__global__ void prep_kernel(const float* __restrict__ X, ushort* __restrict__ Xh,
                            ushort* __restrict__ Xl,
                            const float* __restrict__ W0, unsigned short* __restrict__ Wf0,
                            const float* __restrict__ W1, unsigned short* __restrict__ Wf1,
                            const float* __restrict__ W2, unsigned short* __restrict__ Wf2,
                            int* __restrict__ cnt) {
    int idx = blockIdx.x * 256 + threadIdx.x;
    if (idx < NN) cnt[idx] = 0;
    if (idx < XSPLIT4) {
        float4 v = ((const float4*)X)[idx];
        ushort4 h, l;
        h.x = f2bf(v.x); l.x = f2bf(v.x - bf2f(h.x));
        h.y = f2bf(v.y); l.y = f2bf(v.y - bf2f(h.y));
        h.z = f2bf(v.z); l.z = f2bf(v.z - bf2f(h.z));
        h.w = f2bf(v.w); l.w = f2bf(v.w - bf2f(h.w));
        ((ushort4*)Xh)[idx] = h;
        ((ushort4*)Xl)[idx] = l;
    }
    const int n0 = 4 * 16 * 64;            // K=128
    const int n1 = 8 * 16 * 64;            // K=256
    if (idx < n0) wsplit_one(W0, Wf0, idx);
    else if (idx < n0 + n1) wsplit_one(W1, Wf1, idx - n0);
    else if (idx < n0 + 2 * n1) wsplit_one(W2, Wf2, idx - n0 - n1);
}

// ---------------- MFMA GEMM + fused el/er, LDS-staged A (R12-proven) ----------------
// H[N,256] = (Xhi+Xlo)[N,K] @ W[K,256], bf16 hi/lo (3 MFMA products, lo*lo dropped).
// Block: 64 rows x 256 cols, 4 waves; wave w owns head w's 64 cols.
// A: row-major global -> registers (coalesced 64B/row) -> fragment-major LDS
//    (b128 conflict-free) -> ds_read_b128 fragments. W: fragment-major global.
template <int K>
__global__ __launch_bounds__(256, 3) void mfma_gemm_kernel(
    const ushort* __restrict__ Xh, const ushort* __restrict__ Xl,
    const unsigned short* __restrict__ Wf,
    float* __restrict__ H,
    const float* __restrict__ al, const float* __restrict__ ar,
    float* __restrict__ el, float* __restrict__ er) {
    constexpr int KB = K / 32;     // k-blocks
    __shared__ ushort ldsA[4 * 2 * 64 * 8];   // [r][h][flane][8] = 8 KB
    int tid = threadIdx.x;
    int w = tid >> 6;              // wave index = head
    int lane = tid & 63;
    int rowBase = blockIdx.x * 64;
    int mrow = lane & 15;          // C: col within tile
    int q = lane >> 4;             // quad

    f32x4 acc[4][4];
#pragma unroll
    for (int r = 0; r < 4; r++)
#pragma unroll
        for (int c = 0; c < 4; c++) {
            f32x4 z = {0.f, 0.f, 0.f, 0.f};
            acc[r][c] = z;
        }

    int srow = tid >> 2, qq = tid & 3;
    int grow = rowBase + srow;
    grow = grow < NN ? grow : NN - 1;      // clamp; OOB rows never stored
    const ushort* xhp = Xh + (size_t)grow * K + qq * 8;
    const ushort* xlp = Xl + (size_t)grow * K + qq * 8;
    int sr = srow >> 4, smrow = srow & 15;
    int flane = qq * 16 + smrow;
    ushort* ldsWhi = &ldsA[((size_t)(sr * 2 + 0) * 64 + flane) * 8];
    ushort* ldsWlo = &ldsA[((size_t)(sr * 2 + 1) * 64 + flane) * 8];

    short8 sAh = *(const short8*)xhp;
    short8 sAl = *(const short8*)xlp;

    for (int kb = 0; kb < KB; kb++) {
        __syncthreads();                   // previous iter's LDS reads done
        *(short8*)ldsWhi = sAh;
        *(short8*)ldsWlo = sAl;
        __syncthreads();
        if (kb + 1 < KB) {                 // prefetch next A tile (overlaps compute)
            sAh = *(const short8*)(xhp + (kb + 1) * 32);
            sAl = *(const short8*)(xlp + (kb + 1) * 32);
        }
        short8 Wh[4], Wl_[4];
#pragma unroll
        for (int c = 0; c < 4; c++) {
            const unsigned short* wp =
                Wf + (((size_t)(kb * 16 + w * 4 + c) * 2) * 64 + lane) * 8;
            Wh[c]  = *(const short8*)wp;
            Wl_[c] = *(const short8*)(wp + 512);
        }
        short8 Ah[4], Al_[4];
#pragma unroll
        for (int r = 0; r < 4; r++) {
            Ah[r]  = *(const short8*)&ldsA[((size_t)(r * 2 + 0) * 64 + lane) * 8];
            Al_[r] = *(const short8*)&ldsA[((size_t)(r * 2 + 1) * 64 + lane) * 8];
        }
#pragma unroll
        for (int c = 0; c < 4; c++)
#pragma unroll
            for (int r = 0; r < 4; r++) {
                acc[r][c] = __builtin_amdgcn_mfma_f32_16x16x32_bf16(Ah[r],  Wh[c],  acc[r][c], 0, 0, 0);
                acc[r][c] = __builtin_amdgcn_mfma_f32_16x16x32_bf16(Ah[r],  Wl_[c], acc[r][c], 0, 0, 0);
                acc[r][c] = __builtin_amdgcn_mfma_f32_16x16x32_bf16(Al_[r], Wh[c],  acc[r][c], 0, 0, 0);
            }
    }

    // --- epilogue: store H + fused el/er (head w) ---
    int n0 = w * 64;
    float alv[4], arv[4];
#pragma unroll
    for (int c = 0; c < 4; c++) {
        alv[c] = al[n0 + c * 16 + mrow];
        arv[c] = ar[n0 + c * 16 + mrow];
    }
#pragma unroll
    for (int r = 0; r < 4; r++) {
        float pl[4] = {0.f, 0.f, 0.f, 0.f};
        float pr[4] = {0.f, 0.f, 0.f, 0.f};
#pragma unroll
        for (int c = 0; c < 4; c++)
#pragma unroll
            for (int g = 0; g < 4; g++) {
                pl[g] += acc[r][c][g] * alv[c];
                pr[g] += acc[r][c][g] * arv[c];
            }
#pragma unroll
        for (int g = 0; g < 4; g++) {
#pragma unroll
            for (int off = 1; off < 16; off <<= 1) {
                pl[g] += __shfl_xor(pl[g], off);
                pr[g] += __shfl_xor(pr[g], off);
            }
        }
#pragma unroll
        for (int g = 0; g < 4; g++) {
            int row = rowBase + r * 16 + q * 4 + g;
            if (row < NN) {
#pragma unroll
                for (int c = 0; c < 4; c++)
                    H[(size_t)row * HD + n0 + c * 16 + mrow] = acc[r][c][g];
                if (mrow == 0) {
                    el[row * 4 + w] = pl[g];
                    er[row * 4 + w] = pr[g];
                }
            }
        }
    }
}

// ---------------- GAT per-node: single-pass flash softmax, unroll-2 (R12-proven) ----------------
__device__ __forceinline__ float lrelu(float x) { return x > 0.f ? x : NEG_SLOPE * x; }

template <int FINAL>
__global__ __launch_bounds__(256) void gat_node_kernel(
    const float* __restrict__ H, const float* __restrict__ el, const float* __restrict__ er,
    const int* __restrict__ rowptr, const int* __restrict__ csr_src,
    ushort* __restrict__ out_hi, ushort* __restrict__ out_lo,
    const float* __restrict__ Wout, const float* __restrict__ bout,
    float* __restrict__ final_out) {
    int wave = threadIdx.x >> 6, lane = threadIdx.x & 63;
    int v = blockIdx.x * 4 + wave;
    if (v >= NN) return;
    int beg = rowptr[v], end = rowptr[v + 1];

    int hh = lane >> 4;                    // head for this lane's feature slice
    float er_h = er[v * 4 + hh];

    float m = -INFINITY;
    float ssum = 0.f;
    float4 acc = make_float4(0.f, 0.f, 0.f, 0.f);

    int idx = beg;
    for (; idx + 2 <= end; idx += 2) {
        int s0 = csr_src[idx];
        int s1 = csr_src[idx + 1];
        float el0 = el[s0 * 4 + hh];
        float el1 = el[s1 * 4 + hh];
        float4 h0 = *(const float4*)&H[(long)s0 * HD + lane * 4];
        float4 h1 = *(const float4*)&H[(long)s1 * HD + lane * 4];
        float e0 = lrelu(el0 + er_h);
        float e1 = lrelu(el1 + er_h);
        float mn = fmaxf(m, fmaxf(e0, e1));
        float sc = __expf(m - mn);
        float w0 = __expf(e0 - mn);
        float w1 = __expf(e1 - mn);
        ssum = ssum * sc + w0 + w1;
        acc.x = acc.x * sc + w0 * h0.x + w1 * h1.x;
        acc.y = acc.y * sc + w0 * h0.y + w1 * h1.y;
        acc.z = acc.z * sc + w0 * h0.z + w1 * h1.z;
        acc.w = acc.w * sc + w0 * h0.w + w1 * h1.w;
        m = mn;
    }
    if (idx < end) {
        int s0 = csr_src[idx];
        float el0 = el[s0 * 4 + hh];
        float4 h0 = *(const float4*)&H[(long)s0 * HD + lane * 4];
        float e0 = lrelu(el0 + er_h);
        float mn = fmaxf(m, e0);
        float sc = __expf(m - mn);
        float w0 = __expf(e0 - mn);
        ssum = ssum * sc + w0;
        acc.x = acc.x * sc + w0 * h0.x;
        acc.y = acc.y * sc + w0 * h0.y;
        acc.z = acc.z * sc + w0 * h0.z;
        acc.w = acc.w * sc + w0 * h0.w;
    }

    float inv = 1.0f / (ssum + 1e-9f);
    acc.x *= inv; acc.y *= inv; acc.z *= inv; acc.w *= inv;

    // elu
    acc.x = acc.x > 0.f ? acc.x : expm1f(acc.x);
    acc.y = acc.y > 0.f ? acc.y : expm1f(acc.y);
    acc.z = acc.z > 0.f ? acc.z : expm1f(acc.z);
    acc.w = acc.w > 0.f ? acc.w : expm1f(acc.w);

    if (!FINAL) {
        // row-major hi/lo bf16 (contiguous 512B/row/buffer writes) — next GEMM's A
        ushort4 hv, lv;
        hv.x = f2bf(acc.x); lv.x = f2bf(acc.x - bf2f(hv.x));
        hv.y = f2bf(acc.y); lv.y = f2bf(acc.y - bf2f(hv.y));
        hv.z = f2bf(acc.z); lv.z = f2bf(acc.z - bf2f(hv.z));
        hv.w = f2bf(acc.w); lv.w = f2bf(acc.w - bf2f(hv.w));
        *(ushort4*)&out_hi[(size_t)v * HD + lane * 4] = hv;
        *(ushort4*)&out_lo[(size_t)v * HD + lane * 4] = lv;
    } else {
        // mean over heads (lanes l, l^16, l^32 hold same d-range, different head)
        acc.x += __shfl_xor(acc.x, 16); acc.x += __shfl_xor(acc.x, 32);
        acc.y += __shfl_xor(acc.y, 16); acc.y += __shfl_xor(acc.y, 32);
        acc.z += __shfl_xor(acc.z, 16); acc.z += __shfl_xor(acc.z, 32);
        acc.w += __shfl_xor(acc.w, 16); acc.w += __shfl_xor(acc.w, 32);
        float4 w4 = *(const float4*)&Wout[(lane & 15) * 4];
        float p = 0.25f * (acc.x * w4.x + acc.y * w4.y + acc.z * w4.z + acc.w * w4.w);
        p += __shfl_xor(p, 1);
        p += __shfl_xor(p, 2);
        p += __shfl_xor(p, 4);
        p += __shfl_xor(p, 8);
        if (lane == 0) final_out[v] = fmaxf(p + bout[0], 0.f);
    }
}

extern "C" void kernel_launch(void* const* d_in, const int* in_sizes, int n_in,
                              void* d_out, int out_size, void* d_ws, size_t ws_size,
                              hipStream_t stream) {
    const float* x    = (const float*)d_in[0];
    const int*   src  = (const int*)d_in[1];
    const int*   dst  = (const int*)d_in[2];
    const float* W0   = (const float*)d_in[3];
    const float* al0  = (const float*)d_in[4];
    const float* ar0  = (const float*)d_in[5];
    const float* W1   = (const float*)d_in[6];
    const float* al1  = (const float*)d_in[7];
    const float* ar1  = (const float*)d_in[8];
    const float* W2   = (const float*)d_in[9];
    const float* al2  = (const float*)d_in[10];
    const float* ar2  = (const float*)d_in[11];
    const float* Wout = (const float*)d_in[12];
    const float* bout = (const float*)d_in[13];
    float* outp = (float*)d_out;

    char* ws = (char*)d_ws;
    size_t off = 0;
    auto carve = [&](size_t n) -> char* {
        char* p = ws + off;
        off += (n + 255) & ~(size_t)255;
        return p;
    };
    float*  h_buf  = (float*)carve((size_t)NN * HD * 4);
    ushort* xh     = (ushort*)carve((size_t)NN * HD * 2);   // A hi, row-major
    ushort* xl     = (ushort*)carve((size_t)NN * HD * 2);   // A lo, row-major
    float*  el     = (float*)carve((size_t)NN * HEADS * 4);
    float*  er     = (float*)carve((size_t)NN * HEADS * 4);
    int*    cnt    = (int*)carve((size_t)NN * 4);
    int*    cursor = (int*)carve((size_t)NN * 4);
    int*    rowptr = (int*)carve((size_t)(NN + 1) * 4);
    int*    csr_src= (int*)carve((size_t)NE * 4);
    int*    csum   = (int*)carve(64 * 4);
    unsigned short* Wf0 = (unsigned short*)carve((size_t)4 * 16 * 64 * 16 * 2);   // K=128
    unsigned short* Wf1 = (unsigned short*)carve((size_t)8 * 16 * 64 * 16 * 2);   // K=256
    unsigned short* Wf2 = (unsigned short*)carve((size_t)8 * 16 * 64 * 16 * 2);   // K=256

    // ---- prep: W splits + layer-0 X split + cnt zeroing in one dispatch ----
    prep_kernel<<<(XSPLIT4 + 255) / 256, 256, 0, stream>>>(x, xh, xl, W0, Wf0, W1, Wf1,
                                                           W2, Wf2, cnt);

    // ---- build dst-CSR: count, chunk_sum, rowptr(+cursor), scatter ----
    count_kernel<<<(NE / 4 + 255) / 256, 256, 0, stream>>>(dst, cnt);
    chunk_sum_kernel<<<NCHUNK, 256, 0, stream>>>(cnt, csum, NN);
    rowptr_kernel<<<NCHUNK, 1024, 0, stream>>>(cnt, csum, rowptr, cursor, NN);
    scatter_kernel<<<(NE / 4 + 255) / 256, 256, 0, stream>>>(src, dst, cursor, csr_src);

    int gGemm = (NN + 63) / 64;            // 782
    int gNode = (NN + 3) / 4;

    // ---- layer 0 ----
    mfma_gemm_kernel<128><<<gGemm, 256, 0, stream>>>(xh, xl, Wf0, h_buf, al0, ar0, el, er);
    gat_node_kernel<0><<<gNode, 256, 0, stream>>>(h_buf, el, er, rowptr, csr_src,
                                                  xh, xl, nullptr, nullptr, nullptr);
    // ---- layer 1 ----
    mfma_gemm_kernel<256><<<gGemm, 256, 0, stream>>>(xh, xl, Wf1, h_buf, al1, ar1, el, er);
    gat_node_kernel<0><<<gNode, 256, 0, stream>>>(h_buf, el, er, rowptr, csr_src,
                                                  xh, xl, nullptr, nullptr, nullptr);
    // ---- layer 2 (final: fused elu + head-mean + Wout + relu) ----
    mfma_gemm_kernel<256><<<gGemm, 256, 0, stream>>>(xh, xl, Wf2, h_buf, al2, ar2, el, er);
    gat_node_kernel<1><<<gNode, 256, 0, stream>>>(h_buf, el, er, rowptr, csr_src,
                                                  nullptr, nullptr, Wout, bout, outp);
}